// Round 1
// baseline (448.897 us; speedup 1.0000x reference)
//
#include <hip/hip_runtime.h>

#define BB 8
#define NN 6
#define DD 45
#define CC 64
#define FHH 8
#define FWW 22
#define GXX 64
#define GYY 64
#define GZZ 32
// P = BB*NN*DD*FHH*FWW = 380160 points, 4 points (waves) per 256-thread block
#define NPOINTS (BB*NN*DD*FHH*FWW)

__global__ __launch_bounds__(256) void lss_zero(float4* __restrict__ out, int n4) {
    int i = blockIdx.x * blockDim.x + threadIdx.x;
    int stride = gridDim.x * blockDim.x;
    float4 z = make_float4(0.f, 0.f, 0.f, 0.f);
    for (; i < n4; i += stride) out[i] = z;
}

__global__ __launch_bounds__(256) void lss_scatter(
    const float* __restrict__ depth,     // [B,N,D,FH,FW]
    const float* __restrict__ feature,   // [B,N,C,FH,FW]
    const float* __restrict__ rots,      // [B,N,3,3]
    const float* __restrict__ trans,     // [B,N,3]
    const float* __restrict__ intr,      // [B,N,3,3]
    float* __restrict__ out)             // [B,C,GZ,GX,GY]
{
    int p = blockIdx.x * 4 + (threadIdx.x >> 6);   // point id, wave-uniform
    int lane = threadIdx.x & 63;                   // channel

    // decompose point id -> (b, n, di, h, w)
    int w = p % FWW;
    int t = p / FWW;
    int h = t % FHH; t /= FHH;
    int di = t % DD; t /= DD;
    int n = t % NN;
    int b = t / NN;

    // frustum pixel coords (match jnp.linspace over [0,351]x[0,127]) and depth
    float d = (float)(di + 1);
    float x = (float)(351.0 * (double)w / 21.0);
    float y = (float)(127.0 * (double)h / 7.0);

    // invert K (adjugate in f64, round to f32 ~= np.linalg.inv result)
    const float* K = intr + (b * NN + n) * 9;
    double k00 = K[0], k01 = K[1], k02 = K[2];
    double k10 = K[3], k11 = K[4], k12 = K[5];
    double k20 = K[6], k21 = K[7], k22 = K[8];
    double det = k00 * (k11 * k22 - k12 * k21)
               - k01 * (k10 * k22 - k12 * k20)
               + k02 * (k10 * k21 - k11 * k20);
    double id = 1.0 / det;
    float i00 = (float)(( k11 * k22 - k12 * k21) * id);
    float i01 = (float)((-k01 * k22 + k02 * k21) * id);
    float i02 = (float)(( k01 * k12 - k02 * k11) * id);
    float i10 = (float)((-k10 * k22 + k12 * k20) * id);
    float i11 = (float)(( k00 * k22 - k02 * k20) * id);
    float i12 = (float)((-k00 * k12 + k02 * k10) * id);
    float i20 = (float)(( k10 * k21 - k11 * k20) * id);
    float i21 = (float)((-k00 * k21 + k01 * k20) * id);
    float i22 = (float)(( k00 * k11 - k01 * k10) * id);

    // camera-frame point: inv_K @ [x*d, y*d, d]  (f32, same contraction order as einsum)
    float p0 = x * d, p1 = y * d, p2 = d;
    float c0 = i00 * p0 + i01 * p1 + i02 * p2;
    float c1 = i10 * p0 + i11 * p1 + i12 * p2;
    float c2 = i20 * p0 + i21 * p1 + i22 * p2;

    // world: R @ pc + t
    const float* R = rots + (b * NN + n) * 9;
    const float* T = trans + (b * NN + n) * 3;
    float g0 = R[0] * c0 + R[1] * c1 + R[2] * c2 + T[0];
    float g1 = R[3] * c0 + R[4] * c1 + R[5] * c2 + T[1];
    float g2 = R[6] * c0 + R[7] * c1 + R[8] * c2 + T[2];

    // voxel indices: truncation toward zero matches astype(int32)
    int nx = (int)((g0 + 16.0f) / 0.5f);
    int ny = (int)((g2 + 16.0f) / 0.5f);
    int nz = (int)((g1 + 8.0f)  / 0.5f);
    if (!((nx >= 0) & (nx < GXX) & (ny >= 0) & (ny < GYY) & (nz >= 0) & (nz < GZZ)))
        return;  // wave-uniform early exit

    float dv = depth[(((b * NN + n) * DD + di) * FHH + h) * FWW + w];
    float fv = feature[(((b * NN + n) * CC + lane) * FHH + h) * FWW + w];
    float ctx = dv * fv;

    // out[b, c=lane, nz, nx, ny]
    size_t oidx = ((((size_t)b * CC + lane) * GZZ + nz) * GXX + nx) * GYY + ny;
    atomicAdd(out + oidx, ctx);
}

extern "C" void kernel_launch(void* const* d_in, const int* in_sizes, int n_in,
                              void* d_out, int out_size, void* d_ws, size_t ws_size,
                              hipStream_t stream) {
    const float* depth   = (const float*)d_in[0];
    const float* feature = (const float*)d_in[1];
    const float* rots    = (const float*)d_in[2];
    const float* trans   = (const float*)d_in[3];
    const float* intr    = (const float*)d_in[4];
    float* out = (float*)d_out;

    // 1) zero the 256 MB BEV grid (out_size = 67,108,864 floats, divisible by 4)
    int n4 = out_size / 4;
    lss_zero<<<4096, 256, 0, stream>>>((float4*)out, n4);

    // 2) scatter: one wave per point, lane = channel
    lss_scatter<<<NPOINTS / 4, 256, 0, stream>>>(depth, feature, rots, trans, intr, out);
}

// Round 2
// 265.138 us; speedup vs baseline: 1.6931x; 1.6931x over previous
//
#include <hip/hip_runtime.h>

#define BB 8
#define NN 6
#define DD 45
#define CC 64
#define FHH 8
#define FWW 22
#define GXX 64
#define GYY 64
#define GZZ 32
#define NPOINTS (BB*NN*DD*FHH*FWW)
#define NVOX ((size_t)BB*GZZ*GXX*GYY)            // 1,048,576 voxels
#define SCRATCH_FLOATS (NVOX*CC)                 // 256 MiB worth of floats

__global__ __launch_bounds__(256) void lss_zero(float4* __restrict__ p, int n4) {
    int i = blockIdx.x * blockDim.x + threadIdx.x;
    int stride = gridDim.x * blockDim.x;
    float4 z = make_float4(0.f, 0.f, 0.f, 0.f);
    for (; i < n4; i += stride) p[i] = z;
}

// Computes the point's voxel index (wave-uniform) and returns ctx for this lane's
// channel; returns false if the point is out of the grid.
__device__ __forceinline__ bool point_ctx(
    int p, int lane,
    const float* __restrict__ depth, const float* __restrict__ feature,
    const float* __restrict__ rots, const float* __restrict__ trans,
    const float* __restrict__ intr,
    int& b, int& nx, int& ny, int& nz, float& ctx)
{
    int w = p % FWW;
    int t = p / FWW;
    int h = t % FHH; t /= FHH;
    int di = t % DD; t /= DD;
    int n = t % NN;
    b = t / NN;

    float d = (float)(di + 1);
    float x = (float)(351.0 * (double)w / 21.0);
    float y = (float)(127.0 * (double)h / 7.0);

    const float* K = intr + (b * NN + n) * 9;
    double k00 = K[0], k01 = K[1], k02 = K[2];
    double k10 = K[3], k11 = K[4], k12 = K[5];
    double k20 = K[6], k21 = K[7], k22 = K[8];
    double det = k00 * (k11 * k22 - k12 * k21)
               - k01 * (k10 * k22 - k12 * k20)
               + k02 * (k10 * k21 - k11 * k20);
    double id = 1.0 / det;
    float i00 = (float)(( k11 * k22 - k12 * k21) * id);
    float i01 = (float)((-k01 * k22 + k02 * k21) * id);
    float i02 = (float)(( k01 * k12 - k02 * k11) * id);
    float i10 = (float)((-k10 * k22 + k12 * k20) * id);
    float i11 = (float)(( k00 * k22 - k02 * k20) * id);
    float i12 = (float)((-k00 * k12 + k02 * k10) * id);
    float i20 = (float)(( k10 * k21 - k11 * k20) * id);
    float i21 = (float)((-k00 * k21 + k01 * k20) * id);
    float i22 = (float)(( k00 * k11 - k01 * k10) * id);

    float p0 = x * d, p1 = y * d, p2 = d;
    float c0 = i00 * p0 + i01 * p1 + i02 * p2;
    float c1 = i10 * p0 + i11 * p1 + i12 * p2;
    float c2 = i20 * p0 + i21 * p1 + i22 * p2;

    const float* R = rots + (b * NN + n) * 9;
    const float* T = trans + (b * NN + n) * 3;
    float g0 = R[0] * c0 + R[1] * c1 + R[2] * c2 + T[0];
    float g1 = R[3] * c0 + R[4] * c1 + R[5] * c2 + T[1];
    float g2 = R[6] * c0 + R[7] * c1 + R[8] * c2 + T[2];

    nx = (int)((g0 + 16.0f) / 0.5f);
    ny = (int)((g2 + 16.0f) / 0.5f);
    nz = (int)((g1 + 8.0f)  / 0.5f);
    if (!((nx >= 0) & (nx < GXX) & (ny >= 0) & (ny < GYY) & (nz >= 0) & (nz < GZZ)))
        return false;

    float dv = depth[(((b * NN + n) * DD + di) * FHH + h) * FWW + w];
    float fv = feature[(((b * NN + n) * CC + lane) * FHH + h) * FWW + w];
    ctx = dv * fv;
    return true;
}

// Scatter into channel-last scratch [B,GZ,GX,GY,C]: a wave's 64 atomics are contiguous.
__global__ __launch_bounds__(256) void lss_scatter_cl(
    const float* __restrict__ depth, const float* __restrict__ feature,
    const float* __restrict__ rots, const float* __restrict__ trans,
    const float* __restrict__ intr, float* __restrict__ scratch)
{
    int p = blockIdx.x * 4 + (threadIdx.x >> 6);
    int lane = threadIdx.x & 63;
    int b, nx, ny, nz; float ctx;
    if (!point_ctx(p, lane, depth, feature, rots, trans, intr, b, nx, ny, nz, ctx))
        return;
    size_t v = (((size_t)b * GZZ + nz) * GXX + nx) * GYY + ny;
    atomicAdd(scratch + v * CC + lane, ctx);
}

// Fallback: direct scatter into [B,C,GZ,GX,GY] output (R1 behavior).
__global__ __launch_bounds__(256) void lss_scatter_direct(
    const float* __restrict__ depth, const float* __restrict__ feature,
    const float* __restrict__ rots, const float* __restrict__ trans,
    const float* __restrict__ intr, float* __restrict__ out)
{
    int p = blockIdx.x * 4 + (threadIdx.x >> 6);
    int lane = threadIdx.x & 63;
    int b, nx, ny, nz; float ctx;
    if (!point_ctx(p, lane, depth, feature, rots, trans, intr, b, nx, ny, nz, ctx))
        return;
    size_t oidx = ((((size_t)b * CC + lane) * GZZ + nz) * GXX + nx) * GYY + ny;
    atomicAdd(out + oidx, ctx);
}

// Transpose scratch [B,GZ,GX,GY,C] -> out [B,C,GZ,GX,GY].
// One block per (b,nz,nx) slab = 64(ny) x 64(c) tile.
__global__ __launch_bounds__(256) void lss_transpose(
    const float* __restrict__ s, float* __restrict__ out)
{
    int slab = blockIdx.x;                 // (b*GZ + nz)*GX + nx
    int nx = slab % GXX;
    int t2 = slab / GXX;
    int nz = t2 % GZZ;
    int b  = t2 / GZZ;

    __shared__ float tile[64][65];
    const float4* sp = (const float4*)(s + (size_t)slab * (GYY * CC));
    int tid = threadIdx.x;

    #pragma unroll
    for (int k = 0; k < 4; ++k) {
        int i = tid + k * 256;             // i in [0,1024): float4 index
        int row = i >> 4;                  // ny
        int col4 = i & 15;                 // c/4
        float4 v = sp[i];
        tile[row][col4 * 4 + 0] = v.x;
        tile[row][col4 * 4 + 1] = v.y;
        tile[row][col4 * 4 + 2] = v.z;
        tile[row][col4 * 4 + 3] = v.w;
    }
    __syncthreads();

    #pragma unroll
    for (int k = 0; k < 4; ++k) {
        int i = tid + k * 256;
        int c   = i >> 4;                  // channel
        int ny4 = i & 15;                  // ny/4
        float4 v;
        v.x = tile[ny4 * 4 + 0][c];
        v.y = tile[ny4 * 4 + 1][c];
        v.z = tile[ny4 * 4 + 2][c];
        v.w = tile[ny4 * 4 + 3][c];
        size_t o = ((((size_t)b * CC + c) * GZZ + nz) * GXX + nx) * GYY + ny4 * 4;
        *(float4*)(out + o) = v;
    }
}

extern "C" void kernel_launch(void* const* d_in, const int* in_sizes, int n_in,
                              void* d_out, int out_size, void* d_ws, size_t ws_size,
                              hipStream_t stream) {
    const float* depth   = (const float*)d_in[0];
    const float* feature = (const float*)d_in[1];
    const float* rots    = (const float*)d_in[2];
    const float* trans   = (const float*)d_in[3];
    const float* intr    = (const float*)d_in[4];
    float* out = (float*)d_out;

    if (ws_size >= SCRATCH_FLOATS * sizeof(float)) {
        float* scratch = (float*)d_ws;
        // 1) zero scratch (256 MiB)
        lss_zero<<<4096, 256, 0, stream>>>((float4*)scratch, (int)(SCRATCH_FLOATS / 4));
        // 2) scatter into channel-last scratch (contiguous atomics per wave)
        lss_scatter_cl<<<NPOINTS / 4, 256, 0, stream>>>(depth, feature, rots, trans, intr, scratch);
        // 3) transpose to output layout (writes every output element; no out-zero needed)
        lss_transpose<<<BB * GZZ * GXX, 256, 0, stream>>>(scratch, out);
    } else {
        // Fallback: R1 path
        lss_zero<<<4096, 256, 0, stream>>>((float4*)out, out_size / 4);
        lss_scatter_direct<<<NPOINTS / 4, 256, 0, stream>>>(depth, feature, rots, trans, intr, out);
    }
}

// Round 3
// 108.589 us; speedup vs baseline: 4.1339x; 2.4417x over previous
//
#include <hip/hip_runtime.h>

#define BB 8
#define NN 6
#define DD 45
#define CC 64
#define FHH 8
#define FWW 22
#define GXX 64
#define GYY 64
#define GZZ 32
#define NPOINTS (BB*NN*DD*FHH*FWW)       // 380160
#define NVOX ((size_t)BB*GZZ*GXX*GYY)    // 1,048,576
#define NSITES (BB*NN*FHH*FWW)           // 8448
#define NFEATT (NSITES*CC)               // 540672

// ws layout (bytes): head[NVOX] | next[NPOINTS] | featT[NFEATT]
#define WS_HEAD_OFF 0
#define WS_NEXT_OFF (NVOX * 4)
#define WS_FEATT_OFF (WS_NEXT_OFF + (size_t)NPOINTS * 4)
#define WS_NEEDED (WS_FEATT_OFF + (size_t)NFEATT * 4)

__global__ __launch_bounds__(256) void lss_fill_i4(int4* __restrict__ p, int n4, int val) {
    int i = blockIdx.x * blockDim.x + threadIdx.x;
    int stride = gridDim.x * blockDim.x;
    int4 z = make_int4(val, val, val, val);
    for (; i < n4; i += stride) p[i] = z;
}

__global__ __launch_bounds__(256) void lss_zero(float4* __restrict__ p, int n4) {
    int i = blockIdx.x * blockDim.x + threadIdx.x;
    int stride = gridDim.x * blockDim.x;
    float4 z = make_float4(0.f, 0.f, 0.f, 0.f);
    for (; i < n4; i += stride) p[i] = z;
}

// feature [B,N,C,FH,FW] -> featT [B,N,FH,FW,C]
__global__ __launch_bounds__(256) void lss_featT(const float* __restrict__ feature,
                                                 float* __restrict__ featT) {
    int idx = blockIdx.x * 256 + threadIdx.x;       // < NFEATT
    int c = idx & 63;
    int site = idx >> 6;                             // (cam*FH + h)*FW + w
    int hw = site % (FHH * FWW);
    int cam = site / (FHH * FWW);
    featT[idx] = feature[(cam * CC + c) * (FHH * FWW) + hw];
}

// Per-point geometry -> voxel; push point onto its voxel's linked list.
__global__ __launch_bounds__(256) void lss_build(
    const float* __restrict__ rots, const float* __restrict__ trans,
    const float* __restrict__ intr,
    int* __restrict__ head, int* __restrict__ nxt)
{
    int p = blockIdx.x * 256 + threadIdx.x;          // < NPOINTS
    int w = p % FWW;
    int t = p / FWW;
    int h = t % FHH; t /= FHH;
    int di = t % DD; t /= DD;
    int n = t % NN;
    int b = t / NN;

    float d = (float)(di + 1);
    float x = (float)(351.0 * (double)w / 21.0);
    float y = (float)(127.0 * (double)h / 7.0);

    const float* K = intr + (b * NN + n) * 9;
    double k00 = K[0], k01 = K[1], k02 = K[2];
    double k10 = K[3], k11 = K[4], k12 = K[5];
    double k20 = K[6], k21 = K[7], k22 = K[8];
    double det = k00 * (k11 * k22 - k12 * k21)
               - k01 * (k10 * k22 - k12 * k20)
               + k02 * (k10 * k21 - k11 * k20);
    double id = 1.0 / det;
    float i00 = (float)(( k11 * k22 - k12 * k21) * id);
    float i01 = (float)((-k01 * k22 + k02 * k21) * id);
    float i02 = (float)(( k01 * k12 - k02 * k11) * id);
    float i10 = (float)((-k10 * k22 + k12 * k20) * id);
    float i11 = (float)(( k00 * k22 - k02 * k20) * id);
    float i12 = (float)((-k00 * k12 + k02 * k10) * id);
    float i20 = (float)(( k10 * k21 - k11 * k20) * id);
    float i21 = (float)((-k00 * k21 + k01 * k20) * id);
    float i22 = (float)(( k00 * k11 - k01 * k10) * id);

    float p0 = x * d, p1 = y * d, p2 = d;
    float c0 = i00 * p0 + i01 * p1 + i02 * p2;
    float c1 = i10 * p0 + i11 * p1 + i12 * p2;
    float c2 = i20 * p0 + i21 * p1 + i22 * p2;

    const float* R = rots + (b * NN + n) * 9;
    const float* T = trans + (b * NN + n) * 3;
    float g0 = R[0] * c0 + R[1] * c1 + R[2] * c2 + T[0];
    float g1 = R[3] * c0 + R[4] * c1 + R[5] * c2 + T[1];
    float g2 = R[6] * c0 + R[7] * c1 + R[8] * c2 + T[2];

    int nx = (int)((g0 + 16.0f) / 0.5f);
    int ny = (int)((g2 + 16.0f) / 0.5f);
    int nz = (int)((g1 + 8.0f)  / 0.5f);
    if (!((nx >= 0) & (nx < GXX) & (ny >= 0) & (ny < GYY) & (nz >= 0) & (nz < GZZ)))
        return;

    int v = (((b * GZZ + nz) * GXX + nx) * GYY + ny);
    int old = atomicExch(&head[v], p);
    nxt[p] = old;
}

// One block per (b,nz,nx) slab: 64 ny-voxels x 64 channels.
// Wave per voxel walks the chain; LDS transpose; coalesced dense write.
__global__ __launch_bounds__(256) void lss_out(
    const float* __restrict__ depth, const float* __restrict__ featT,
    const int* __restrict__ head, const int* __restrict__ nxt,
    float* __restrict__ out)
{
    int slab = blockIdx.x;                 // (b*GZ + nz)*GX + nx
    int nx = slab % GXX;
    int t2 = slab / GXX;
    int nz = t2 % GZZ;
    int b  = t2 / GZZ;
    int wid = threadIdx.x >> 6;
    int lane = threadIdx.x & 63;

    __shared__ float tile[64][65];
    int vbase = slab * GYY;

    #pragma unroll 1
    for (int i = 0; i < 16; ++i) {
        int ny = i * 4 + wid;
        float acc = 0.f;
        int p = head[vbase + ny];
        while (p >= 0) {
            float dval = depth[p];                  // depth layout == point order
            int rem = p / FWW;  int w = p - rem * FWW;
            int rem2 = rem / FHH; int h = rem - rem2 * FHH;
            int cam = rem2 / DD;
            int site = (cam * FHH + h) * FWW + w;
            acc += dval * featT[site * 64 + lane];  // 256B contiguous per wave
            p = nxt[p];
        }
        tile[ny][lane] = acc;
    }
    __syncthreads();

    int tid = threadIdx.x;
    #pragma unroll
    for (int k = 0; k < 4; ++k) {
        int i = tid + k * 256;
        int c   = i >> 4;
        int ny4 = i & 15;
        float4 v;
        v.x = tile[ny4 * 4 + 0][c];
        v.y = tile[ny4 * 4 + 1][c];
        v.z = tile[ny4 * 4 + 2][c];
        v.w = tile[ny4 * 4 + 3][c];
        size_t o = ((((size_t)b * CC + c) * GZZ + nz) * GXX + nx) * GYY + ny4 * 4;
        *(float4*)(out + o) = v;
    }
}

// ---- fallback (R1 path) ----
__global__ __launch_bounds__(256) void lss_scatter_direct(
    const float* __restrict__ depth, const float* __restrict__ feature,
    const float* __restrict__ rots, const float* __restrict__ trans,
    const float* __restrict__ intr, float* __restrict__ out)
{
    int p = blockIdx.x * 4 + (threadIdx.x >> 6);
    int lane = threadIdx.x & 63;
    int w = p % FWW;
    int t = p / FWW;
    int h = t % FHH; t /= FHH;
    int di = t % DD; t /= DD;
    int n = t % NN;
    int b = t / NN;
    float d = (float)(di + 1);
    float x = (float)(351.0 * (double)w / 21.0);
    float y = (float)(127.0 * (double)h / 7.0);
    const float* K = intr + (b * NN + n) * 9;
    double k00 = K[0], k01 = K[1], k02 = K[2];
    double k10 = K[3], k11 = K[4], k12 = K[5];
    double k20 = K[6], k21 = K[7], k22 = K[8];
    double det = k00*(k11*k22-k12*k21) - k01*(k10*k22-k12*k20) + k02*(k10*k21-k11*k20);
    double id = 1.0 / det;
    float i00=(float)((k11*k22-k12*k21)*id), i01=(float)((-k01*k22+k02*k21)*id), i02=(float)((k01*k12-k02*k11)*id);
    float i10=(float)((-k10*k22+k12*k20)*id), i11=(float)((k00*k22-k02*k20)*id), i12=(float)((-k00*k12+k02*k10)*id);
    float i20=(float)((k10*k21-k11*k20)*id), i21=(float)((-k00*k21+k01*k20)*id), i22=(float)((k00*k11-k01*k10)*id);
    float p0 = x * d, p1 = y * d, p2 = d;
    float c0 = i00*p0 + i01*p1 + i02*p2;
    float c1 = i10*p0 + i11*p1 + i12*p2;
    float c2 = i20*p0 + i21*p1 + i22*p2;
    const float* R = rots + (b * NN + n) * 9;
    const float* T = trans + (b * NN + n) * 3;
    float g0 = R[0]*c0 + R[1]*c1 + R[2]*c2 + T[0];
    float g1 = R[3]*c0 + R[4]*c1 + R[5]*c2 + T[1];
    float g2 = R[6]*c0 + R[7]*c1 + R[8]*c2 + T[2];
    int nx = (int)((g0 + 16.0f) / 0.5f);
    int ny = (int)((g2 + 16.0f) / 0.5f);
    int nz = (int)((g1 + 8.0f)  / 0.5f);
    if (!((nx >= 0) & (nx < GXX) & (ny >= 0) & (ny < GYY) & (nz >= 0) & (nz < GZZ)))
        return;
    float dv = depth[(((b * NN + n) * DD + di) * FHH + h) * FWW + w];
    float fv = feature[(((b * NN + n) * CC + lane) * FHH + h) * FWW + w];
    size_t oidx = ((((size_t)b * CC + lane) * GZZ + nz) * GXX + nx) * GYY + ny;
    atomicAdd(out + oidx, dv * fv);
}

extern "C" void kernel_launch(void* const* d_in, const int* in_sizes, int n_in,
                              void* d_out, int out_size, void* d_ws, size_t ws_size,
                              hipStream_t stream) {
    const float* depth   = (const float*)d_in[0];
    const float* feature = (const float*)d_in[1];
    const float* rots    = (const float*)d_in[2];
    const float* trans   = (const float*)d_in[3];
    const float* intr    = (const float*)d_in[4];
    float* out = (float*)d_out;

    if (ws_size >= WS_NEEDED) {
        int*   head  = (int*)((char*)d_ws + WS_HEAD_OFF);
        int*   nxt   = (int*)((char*)d_ws + WS_NEXT_OFF);
        float* featT = (float*)((char*)d_ws + WS_FEATT_OFF);

        // 1) head = -1 (NVOX ints = 262144 int4)
        lss_fill_i4<<<1024, 256, 0, stream>>>((int4*)head, (int)(NVOX / 4), -1);
        // 2) feature -> channel-last featT (NFEATT = 2112*256)
        lss_featT<<<NFEATT / 256, 256, 0, stream>>>(feature, featT);
        // 3) build per-voxel linked lists (NPOINTS = 1485*256)
        lss_build<<<NPOINTS / 256, 256, 0, stream>>>(rots, trans, intr, head, nxt);
        // 4) dense output generation (writes every element; no out-zero needed)
        lss_out<<<BB * GZZ * GXX, 256, 0, stream>>>(depth, featT, head, nxt, out);
    } else {
        lss_zero<<<4096, 256, 0, stream>>>((float4*)out, out_size / 4);
        lss_scatter_direct<<<NPOINTS / 4, 256, 0, stream>>>(depth, feature, rots, trans, intr, out);
    }
}